// Round 8
// baseline (262.118 us; speedup 1.0000x reference)
//
#include <hip/hip_runtime.h>
#include <hip/hip_bf16.h>
#include <cstdint>

// ---------------------------------------------------------------------------
// CausalSelfAttention: x@Wqkv+b -> heads -> causal flash attn -> @Wproj+b
// B=2 T=2048 C=1024 H=16 Dh=64.
// Attention: barrier-light MFMA on fragment-order K/V (KF/VF written by the
// QKV GEMM epilogue), S^T = K.Q^T, exp2-domain softmax, no running max.
// Load balance: wave = (32-row q-group, k-parity); block pairs (u, 63-u) x
// parities -> every block does exactly 33 tiles; parity partials combine
// exactly in LDS.  NOTE: no min-waves launch_bounds -- R7 showed
// __launch_bounds__(256,4) forces VGPR=64 and spills ~380MB to scratch.
// ---------------------------------------------------------------------------

using u16 = unsigned short;
using u32 = unsigned int;

typedef __bf16 bf16x8 __attribute__((ext_vector_type(8)));
typedef float f32x4 __attribute__((ext_vector_type(4)));

#define AS1 __attribute__((address_space(1)))
#define AS3 __attribute__((address_space(3)))

__device__ __forceinline__ u16 f2bf(float f) {
  u32 u = __float_as_uint(f);
  u += 0x7fffu + ((u >> 16) & 1u);   // RTNE
  return (u16)(u >> 16);
}
// pack two positive floats -> two bf16
__device__ __forceinline__ u32 pack2bf(float a, float b) {
  u32 ua = __float_as_uint(a) + 0x8000u;
  u32 ub = __float_as_uint(b) + 0x8000u;
  return (ua >> 16) | (ub & 0xffff0000u);
}

// ---------------- prep: cvt x->bf16 (blocks 0..4095) + W transposes ---------
__global__ __launch_bounds__(256) void prep(const float* __restrict__ x,
                                            u16* __restrict__ xb,
                                            const float* __restrict__ W0,
                                            u16* __restrict__ T0,
                                            const float* __restrict__ W1,
                                            u16* __restrict__ T1) {
  const int bx = blockIdx.x;
  const int tid = threadIdx.x;
  if (bx < 4096) {
    const int i = bx * 256 + tid;
    float4 v = ((const float4*)x)[i];
    ushort4 o;
    o.x = f2bf(v.x); o.y = f2bf(v.y); o.z = f2bf(v.z); o.w = f2bf(v.w);
    ((ushort4*)xb)[i] = o;
    return;
  }
  __shared__ float t[32][33];
  const int idx = bx - 4096;          // 128 n-tiles x 32 k-tiles
  const int bxx = idx & 127, by = idx >> 7;
  const float* W; u16* Wt; int N, n0;
  if (bxx < 96) { W = W0; Wt = T0; N = 3072; n0 = bxx * 32; }
  else          { W = W1; Wt = T1; N = 1024; n0 = (bxx - 96) * 32; }
  const int k0 = by * 32;
  const int tx = tid & 31, ty = tid >> 5;
#pragma unroll
  for (int i = 0; i < 4; ++i)
    t[ty + i * 8][tx] = W[(size_t)(k0 + ty + i * 8) * N + n0 + tx];
  __syncthreads();
#pragma unroll
  for (int i = 0; i < 4; ++i)
    Wt[(size_t)(n0 + ty + i * 8) * 1024 + k0 + tx] = f2bf(t[tx][ty + i * 8]);
}

// ---------------- QKV GEMM: 128x128 tile (m97 structure) --------------------
// n<1024: Q (scaled by cs) -> qb[4096][1024]
// 1024<=n<2048: K -> KF fragment order [bh][kt][m][hh][lane][8]
// n>=2048:     V -> VF fragment order [bh][kt][hh][di][lane][8] (k-permuted)
__global__ __launch_bounds__(256) void gemm_qkv(const u16* __restrict__ A,
                                                const u16* __restrict__ Bt,
                                                const float* __restrict__ bias,
                                                u16* __restrict__ qb,
                                                u16* __restrict__ KF,
                                                u16* __restrict__ VF,
                                                float sc_val) {
  constexpr int BM = 128, BK = 32;
  constexpr int K = 1024;
  __shared__ __align__(16) u16 lA[BM * BK];
  __shared__ __align__(16) u16 lB[BM * BK];
  const int tid  = threadIdx.x;
  const int lane = tid & 63;
  const int wave = tid >> 6;
  const int bm = blockIdx.x * BM;
  const int bn = blockIdx.y * BM;
  const int wr = (wave >> 1) * 64;
  const int wc = (wave & 1) * 64;

  f32x4 acc[4][4] = {};

  const int f0 = (wave << 10) + (lane << 4);
  const int f1 = f0 + 4096;
  const int r0 = f0 >> 6, c0 = (f0 & 63) >> 1;
  const int r1 = f1 >> 6, c1 = (f1 & 63) >> 1;

  const int arow = wr + (lane & 15);
  const int brow = wc + (lane & 15);
  const int kk   = (lane >> 4) << 3;

  for (int k0 = 0; k0 < K; k0 += BK) {
    __builtin_amdgcn_global_load_lds((AS1 const void*)(A + (size_t)(bm + r0) * K + k0 + c0),
                                     (AS3 void*)(lA + (wave << 9)), 16, 0, 0);
    __builtin_amdgcn_global_load_lds((AS1 const void*)(A + (size_t)(bm + r1) * K + k0 + c1),
                                     (AS3 void*)(lA + ((wave + 4) << 9)), 16, 0, 0);
    __builtin_amdgcn_global_load_lds((AS1 const void*)(Bt + (size_t)(bn + r0) * K + k0 + c0),
                                     (AS3 void*)(lB + (wave << 9)), 16, 0, 0);
    __builtin_amdgcn_global_load_lds((AS1 const void*)(Bt + (size_t)(bn + r1) * K + k0 + c1),
                                     (AS3 void*)(lB + ((wave + 4) << 9)), 16, 0, 0);
    __syncthreads();

    bf16x8 af[4], bfr[4];
#pragma unroll
    for (int mi = 0; mi < 4; ++mi)
      af[mi] = *(const bf16x8*)&lA[(arow + mi * 16) * BK + kk];
#pragma unroll
    for (int ni = 0; ni < 4; ++ni)
      bfr[ni] = *(const bf16x8*)&lB[(brow + ni * 16) * BK + kk];
#pragma unroll
    for (int mi = 0; mi < 4; ++mi)
#pragma unroll
      for (int ni = 0; ni < 4; ++ni)
        acc[mi][ni] = __builtin_amdgcn_mfma_f32_16x16x32_bf16(af[mi], bfr[ni],
                                                              acc[mi][ni], 0, 0, 0);
    __syncthreads();
  }

  const int crow0 = bm + wr + ((lane >> 4) << 2);
  const int ccol0 = bn + wc + (lane & 15);
  if (bn < 1024) {                      // ---- Q (scaled) ----
#pragma unroll
    for (int ni = 0; ni < 4; ++ni) {
      const int n = ccol0 + ni * 16;
      const float bv = bias[n];
#pragma unroll
      for (int mi = 0; mi < 4; ++mi) {
        const int m0 = crow0 + mi * 16;
#pragma unroll
        for (int r = 0; r < 4; ++r)
          qb[(size_t)(m0 + r) * 1024 + n] = f2bf((acc[mi][ni][r] + bv) * sc_val);
      }
    }
  } else if (bn < 2048) {               // ---- K fragment order ----
#pragma unroll
    for (int ni = 0; ni < 4; ++ni) {
      const int n  = ccol0 + ni * 16;
      const int hk = (n - 1024) >> 6;
      const int d  = (n - 1024) & 63;
      const int hh = d >> 5, qd = (d >> 3) & 3, j = d & 7;
      const float bv = bias[n];
#pragma unroll
      for (int mi = 0; mi < 4; ++mi) {
#pragma unroll
        for (int r = 0; r < 4; ++r) {
          const int t  = crow0 + mi * 16 + r;
          const int bb = t >> 11, tt = t & 2047;
          const int kt = tt >> 6, mm = (tt >> 4) & 3, l = tt & 15;
          KF[((size_t)((bb * 16 + hk) * 32 + kt) * 8 + mm * 2 + hh) * 512 +
             (qd * 16 + l) * 8 + j] = f2bf(acc[mi][ni][r] + bv);
        }
      }
    }
  } else {                              // ---- V fragment order (k-perm) ----
#pragma unroll
    for (int ni = 0; ni < 4; ++ni) {
      const int n  = ccol0 + ni * 16;
      const int hv = (n - 2048) >> 6;
      const int d  = (n - 2048) & 63;
      const int di = d >> 4, l = d & 15;
      const float bv = bias[n];
#pragma unroll
      for (int mi = 0; mi < 4; ++mi) {
#pragma unroll
        for (int r = 0; r < 4; ++r) {
          const int t  = crow0 + mi * 16 + r;
          const int bb = t >> 11, tt = t & 2047;
          const int kt = tt >> 6, to = tt & 63;
          const int mq = to >> 4, qd2 = (to >> 2) & 3, rr = to & 3;
          const int hh = mq >> 1, j = (mq & 1) * 4 + rr;
          VF[((size_t)((bb * 16 + hv) * 32 + kt) * 8 + hh * 4 + di) * 512 +
             (qd2 * 16 + l) * 8 + j] = f2bf(acc[mi][ni][r] + bv);
        }
      }
    }
  }
}

// ---------------- Proj GEMM: 128x64 tile, fp32 out --------------------------
__global__ __launch_bounds__(256) void gemm_proj(const u16* __restrict__ A,
                                                 const u16* __restrict__ Bt,
                                                 const float* __restrict__ bias,
                                                 float* __restrict__ C) {
  constexpr int BM = 128, BN = 64, BK = 32;
  constexpr int K = 1024, N = 1024;
  __shared__ __align__(16) u16 lA[BM * BK];
  __shared__ __align__(16) u16 lB[BN * BK];
  const int tid  = threadIdx.x;
  const int lane = tid & 63;
  const int wave = tid >> 6;
  const int bm = blockIdx.x * BM;
  const int bn = blockIdx.y * BN;
  const int wr = wave * 32;

  f32x4 acc[2][4] = {};

  const int f0 = (wave << 10) + (lane << 4);
  const int f1 = f0 + 4096;
  const int ar0 = f0 >> 6, ac0 = (f0 & 63) >> 1;
  const int ar1 = f1 >> 6, ac1 = (f1 & 63) >> 1;

  const int arow = wr + (lane & 15);
  const int brow = (lane & 15);
  const int kk   = (lane >> 4) << 3;

  for (int k0 = 0; k0 < K; k0 += BK) {
    __builtin_amdgcn_global_load_lds((AS1 const void*)(A + (size_t)(bm + ar0) * K + k0 + ac0),
                                     (AS3 void*)(lA + (wave << 9)), 16, 0, 0);
    __builtin_amdgcn_global_load_lds((AS1 const void*)(A + (size_t)(bm + ar1) * K + k0 + ac1),
                                     (AS3 void*)(lA + ((wave + 4) << 9)), 16, 0, 0);
    __builtin_amdgcn_global_load_lds((AS1 const void*)(Bt + (size_t)(bn + ar0) * K + k0 + ac0),
                                     (AS3 void*)(lB + (wave << 9)), 16, 0, 0);
    __syncthreads();

    bf16x8 af[2], bfr[4];
#pragma unroll
    for (int mi = 0; mi < 2; ++mi)
      af[mi] = *(const bf16x8*)&lA[(arow + mi * 16) * BK + kk];
#pragma unroll
    for (int ni = 0; ni < 4; ++ni)
      bfr[ni] = *(const bf16x8*)&lB[(brow + ni * 16) * BK + kk];
#pragma unroll
    for (int mi = 0; mi < 2; ++mi)
#pragma unroll
      for (int ni = 0; ni < 4; ++ni)
        acc[mi][ni] = __builtin_amdgcn_mfma_f32_16x16x32_bf16(af[mi], bfr[ni],
                                                              acc[mi][ni], 0, 0, 0);
    __syncthreads();
  }

  const int crow0 = bm + wr + ((lane >> 4) << 2);
  const int ccol0 = bn + (lane & 15);
#pragma unroll
  for (int ni = 0; ni < 4; ++ni) {
    const int n = ccol0 + ni * 16;
    const float bv = bias[n];
#pragma unroll
    for (int mi = 0; mi < 2; ++mi) {
      const int m0 = crow0 + mi * 16;
#pragma unroll
      for (int r = 0; r < 4; ++r)
        C[(size_t)(m0 + r) * N + n] = acc[mi][ni][r] + bv;
    }
  }
}

// ---------------- balanced MFMA flash attention -----------------------------
// grid (32 u, 32 bh); block 256 = 4 waves.
// wave w: g32 = (w&1) ? 63-u : u  (32 q rows at g32*32), par = w>>1.
// Wave iterates kt = par, par+2, ... <= ktmax(g32) -> every block does
// exactly 33 tiles.  Parity partials combine exactly via LDS (no-max softmax
// => plain sums), par==0 waves normalize and store.  Mask only on kt==ktmax.
__global__ __launch_bounds__(256) void attn_bal(const u16* __restrict__ qb,
                                                const u16* __restrict__ KF,
                                                const u16* __restrict__ VF,
                                                u16* __restrict__ out) {
  const int u  = blockIdx.x;
  const int bh = blockIdx.y;
  const int b = bh >> 4, h = bh & 15;
  const int tid = threadIdx.x;
  const int lane = tid & 63;
  const int w    = tid >> 6;
  const int quad = lane >> 4;
  const int l15  = lane & 15;
  const int g32 = (w & 1) ? (63 - u) : u;
  const int par = w >> 1;
  const int q0 = g32 * 32;
  const int ktmax = g32 >> 1;

  __shared__ float CB[2][64][35];     // [unit][lane][32 accO + 2 lsum]

  // Q B-frags, held all kernel
  const u16* qbase = qb + (size_t)b * 2048 * 1024 + h * 64;
  bf16x8 qf[2][2];
#pragma unroll
  for (int g = 0; g < 2; ++g)
#pragma unroll
    for (int hh = 0; hh < 2; ++hh)
      qf[g][hh] = *(const bf16x8*)(qbase + (size_t)(q0 + g * 16 + l15) * 1024 +
                                   hh * 32 + quad * 8);

  const size_t fb = (size_t)bh * 32 * 4096 + lane * 8;
  const u16* kfb = KF + fb;
  const u16* vfb = VF + fb;

  f32x4 accO[2][4] = {};              // [g][di]: q=quad*4+r, d=di*16+l15
  float lrow[2] = {0.f, 0.f};

  for (int kt = par; kt <= ktmax; kt += 2) {
    const u16* kp = kfb + (size_t)kt * 4096;
    const u16* vp = vfb + (size_t)kt * 4096;
    bf16x8 kfr[4][2];
#pragma unroll
    for (int m = 0; m < 4; ++m)
#pragma unroll
      for (int hh = 0; hh < 2; ++hh)
        kfr[m][hh] = *(const bf16x8*)(kp + (m * 2 + hh) * 512);

    const bool diag = (kt == ktmax);
    bf16x8 ap[2][2];
#pragma unroll
    for (int g = 0; g < 2; ++g) {
      f32x4 sT[4] = {};
#pragma unroll
      for (int m = 0; m < 4; ++m) {
        sT[m] = __builtin_amdgcn_mfma_f32_16x16x32_bf16(kfr[m][0], qf[g][0], sT[m], 0, 0, 0);
        sT[m] = __builtin_amdgcn_mfma_f32_16x16x32_bf16(kfr[m][1], qf[g][1], sT[m], 0, 0, 0);
      }
      float pv[4][4];
      float ps = 0.f;
      if (diag) {                      // only the last tile pays mask ops
        const int qgl = q0 + g * 16 + l15;
#pragma unroll
        for (int m = 0; m < 4; ++m)
#pragma unroll
          for (int r = 0; r < 4; ++r) {
            const bool msk = (kt * 64 + m * 16 + quad * 4 + r) > qgl;
            const float p = msk ? 0.f : __builtin_amdgcn_exp2f(sT[m][r]);
            pv[m][r] = p;
            ps += p;
          }
      } else {
#pragma unroll
        for (int m = 0; m < 4; ++m)
#pragma unroll
          for (int r = 0; r < 4; ++r) {
            const float p = __builtin_amdgcn_exp2f(sT[m][r]);
            pv[m][r] = p;
            ps += p;
          }
      }
      ps += __shfl_xor(ps, 16);
      ps += __shfl_xor(ps, 32);
      lrow[g] += ps;
      union { u32 u4[4]; bf16x8 v; } t0, t1;
      t0.u4[0] = pack2bf(pv[0][0], pv[0][1]);
      t0.u4[1] = pack2bf(pv[0][2], pv[0][3]);
      t0.u4[2] = pack2bf(pv[1][0], pv[1][1]);
      t0.u4[3] = pack2bf(pv[1][2], pv[1][3]);
      t1.u4[0] = pack2bf(pv[2][0], pv[2][1]);
      t1.u4[1] = pack2bf(pv[2][2], pv[2][3]);
      t1.u4[2] = pack2bf(pv[3][0], pv[3][1]);
      t1.u4[3] = pack2bf(pv[3][2], pv[3][3]);
      ap[g][0] = t0.v;
      ap[g][1] = t1.v;
    }

    // O += P.V  (V-frags loaded here, after K-frags are dead)
#pragma unroll
    for (int hh = 0; hh < 2; ++hh)
#pragma unroll
      for (int di = 0; di < 4; ++di) {
        bf16x8 bv = *(const bf16x8*)(vp + (hh * 4 + di) * 512);
#pragma unroll
        for (int g = 0; g < 2; ++g)
          accO[g][di] = __builtin_amdgcn_mfma_f32_16x16x32_bf16(ap[g][hh], bv,
                                                               accO[g][di], 0, 0, 0);
      }
  }

  // ---- exact parity combine ----
  if (par) {
    float* cb = CB[w & 1][lane];
#pragma unroll
    for (int g = 0; g < 2; ++g)
#pragma unroll
      for (int di = 0; di < 4; ++di)
#pragma unroll
        for (int r = 0; r < 4; ++r)
          cb[g * 16 + di * 4 + r] = accO[g][di][r];
    cb[32] = lrow[0];
    cb[33] = lrow[1];
  }
  __syncthreads();
  if (!par) {
    const float* cb = CB[w & 1][lane];
#pragma unroll
    for (int g = 0; g < 2; ++g)
#pragma unroll
      for (int di = 0; di < 4; ++di)
#pragma unroll
        for (int r = 0; r < 4; ++r)
          accO[g][di][r] += cb[g * 16 + di * 4 + r];
    lrow[0] += cb[32];
    lrow[1] += cb[33];

#pragma unroll
    for (int g = 0; g < 2; ++g)
#pragma unroll
      for (int r = 0; r < 4; ++r) {
        const float lv = __shfl(lrow[g], quad * 4 + r);
        const float inv = 1.f / lv;
        const int q = q0 + g * 16 + quad * 4 + r;
        u16* op = out + (size_t)(b * 2048 + q) * 1024 + h * 64 + l15;
#pragma unroll
        for (int di = 0; di < 4; ++di)
          op[di * 16] = f2bf(accO[g][di][r] * inv);
      }
  }
}

// ---------------------------------------------------------------------------
extern "C" void kernel_launch(void* const* d_in, const int* in_sizes, int n_in,
                              void* d_out, int out_size, void* d_ws, size_t ws_size,
                              hipStream_t stream) {
  const float* x     = (const float*)d_in[0];
  const float* Wqkv  = (const float*)d_in[1];
  const float* bqkv  = (const float*)d_in[2];
  const float* Wproj = (const float*)d_in[3];
  const float* bproj = (const float*)d_in[4];
  float* out = (float*)d_out;

  char* ws = (char*)d_ws;
  u16* xb     = (u16*)(ws);                 //  8 MB  x bf16 [4096,1024]
  u16* wqkvT  = (u16*)(ws + 8388608);       //  6 MB  Wqkv^T bf16 [3072,1024]
  u16* wprojT = (u16*)(ws + 14680064);      //  2 MB  Wproj^T bf16 [1024,1024]
  u16* qb     = (u16*)(ws + 16777216);      //  8 MB  Q bf16 [4096,1024] (pre-scaled)
  u16* KF     = (u16*)(ws + 25165824);      //  8 MB  K fragment-order
  u16* VF     = (u16*)(ws + 33554432);      //  8 MB  V fragment-order (k-perm)
  u16* att    = (u16*)(ws + 41943040);      //  8 MB  attn out bf16 [4096,1024]

  constexpr float cs = 0.18033688011f;      // log2(e)/8

  prep<<<8192, 256, 0, stream>>>(x, xb, Wqkv, wqkvT, Wproj, wprojT);

  gemm_qkv<<<dim3(32, 24), 256, 0, stream>>>(xb, wqkvT, bqkv, qb, KF, VF, cs);

  attn_bal<<<dim3(32, 32), 256, 0, stream>>>(qb, KF, VF, att);

  gemm_proj<<<dim3(32, 16), 256, 0, stream>>>(att, wprojT, bproj, out);
}

// Round 9
// 195.947 us; speedup vs baseline: 1.3377x; 1.3377x over previous
//
#include <hip/hip_runtime.h>
#include <hip/hip_bf16.h>
#include <cstdint>

// ---------------------------------------------------------------------------
// CausalSelfAttention: x@Wqkv+b -> heads -> causal flash attn -> @Wproj+b
// B=2 T=2048 C=1024 H=16 Dh=64.
// Attention: barrier-light MFMA on fragment-order K/V (KF/VF written by the
// QKV GEMM epilogue), S^T = K.Q^T, exp2-domain softmax, no running max.
// Load balance: wave = (32-row q-group, k-parity); block pairs (u, 63-u) x
// parities -> every block does exactly 33 tiles; parity partials combine
// exactly in LDS.
// HARD-WON NOTES:
//  - R7: __launch_bounds__(256,4) forced VGPR=64 -> 380MB scratch spills.
//  - R8: moving V-frag loads after softmax doubled per-tile exposed latency
//    (118us vs 53us).  ALL 16 frag loads must issue at tile top so one
//    vmcnt drain covers the tile.
// ---------------------------------------------------------------------------

using u16 = unsigned short;
using u32 = unsigned int;

typedef __bf16 bf16x8 __attribute__((ext_vector_type(8)));
typedef float f32x4 __attribute__((ext_vector_type(4)));

#define AS1 __attribute__((address_space(1)))
#define AS3 __attribute__((address_space(3)))

__device__ __forceinline__ u16 f2bf(float f) {
  u32 u = __float_as_uint(f);
  u += 0x7fffu + ((u >> 16) & 1u);   // RTNE
  return (u16)(u >> 16);
}
// pack two positive floats -> two bf16
__device__ __forceinline__ u32 pack2bf(float a, float b) {
  u32 ua = __float_as_uint(a) + 0x8000u;
  u32 ub = __float_as_uint(b) + 0x8000u;
  return (ua >> 16) | (ub & 0xffff0000u);
}

// ---------------- prep: cvt x->bf16 (blocks 0..4095) + W transposes ---------
__global__ __launch_bounds__(256) void prep(const float* __restrict__ x,
                                            u16* __restrict__ xb,
                                            const float* __restrict__ W0,
                                            u16* __restrict__ T0,
                                            const float* __restrict__ W1,
                                            u16* __restrict__ T1) {
  const int bx = blockIdx.x;
  const int tid = threadIdx.x;
  if (bx < 4096) {
    const int i = bx * 256 + tid;
    float4 v = ((const float4*)x)[i];
    ushort4 o;
    o.x = f2bf(v.x); o.y = f2bf(v.y); o.z = f2bf(v.z); o.w = f2bf(v.w);
    ((ushort4*)xb)[i] = o;
    return;
  }
  __shared__ float t[32][33];
  const int idx = bx - 4096;          // 128 n-tiles x 32 k-tiles
  const int bxx = idx & 127, by = idx >> 7;
  const float* W; u16* Wt; int N, n0;
  if (bxx < 96) { W = W0; Wt = T0; N = 3072; n0 = bxx * 32; }
  else          { W = W1; Wt = T1; N = 1024; n0 = (bxx - 96) * 32; }
  const int k0 = by * 32;
  const int tx = tid & 31, ty = tid >> 5;
#pragma unroll
  for (int i = 0; i < 4; ++i)
    t[ty + i * 8][tx] = W[(size_t)(k0 + ty + i * 8) * N + n0 + tx];
  __syncthreads();
#pragma unroll
  for (int i = 0; i < 4; ++i)
    Wt[(size_t)(n0 + ty + i * 8) * 1024 + k0 + tx] = f2bf(t[tx][ty + i * 8]);
}

// ---------------- QKV GEMM: 128x128 tile (m97 structure) --------------------
// n<1024: Q (scaled by cs) -> qb[4096][1024]
// 1024<=n<2048: K -> KF fragment order [bh][kt][m][hh][lane][8]
// n>=2048:     V -> VF fragment order [bh][kt][hh][di][lane][8] (k-permuted)
__global__ __launch_bounds__(256) void gemm_qkv(const u16* __restrict__ A,
                                                const u16* __restrict__ Bt,
                                                const float* __restrict__ bias,
                                                u16* __restrict__ qb,
                                                u16* __restrict__ KF,
                                                u16* __restrict__ VF,
                                                float sc_val) {
  constexpr int BM = 128, BK = 32;
  constexpr int K = 1024;
  __shared__ __align__(16) u16 lA[BM * BK];
  __shared__ __align__(16) u16 lB[BM * BK];
  const int tid  = threadIdx.x;
  const int lane = tid & 63;
  const int wave = tid >> 6;
  const int bm = blockIdx.x * BM;
  const int bn = blockIdx.y * BM;
  const int wr = (wave >> 1) * 64;
  const int wc = (wave & 1) * 64;

  f32x4 acc[4][4] = {};

  const int f0 = (wave << 10) + (lane << 4);
  const int f1 = f0 + 4096;
  const int r0 = f0 >> 6, c0 = (f0 & 63) >> 1;
  const int r1 = f1 >> 6, c1 = (f1 & 63) >> 1;

  const int arow = wr + (lane & 15);
  const int brow = wc + (lane & 15);
  const int kk   = (lane >> 4) << 3;

  for (int k0 = 0; k0 < K; k0 += BK) {
    __builtin_amdgcn_global_load_lds((AS1 const void*)(A + (size_t)(bm + r0) * K + k0 + c0),
                                     (AS3 void*)(lA + (wave << 9)), 16, 0, 0);
    __builtin_amdgcn_global_load_lds((AS1 const void*)(A + (size_t)(bm + r1) * K + k0 + c1),
                                     (AS3 void*)(lA + ((wave + 4) << 9)), 16, 0, 0);
    __builtin_amdgcn_global_load_lds((AS1 const void*)(Bt + (size_t)(bn + r0) * K + k0 + c0),
                                     (AS3 void*)(lB + (wave << 9)), 16, 0, 0);
    __builtin_amdgcn_global_load_lds((AS1 const void*)(Bt + (size_t)(bn + r1) * K + k0 + c1),
                                     (AS3 void*)(lB + ((wave + 4) << 9)), 16, 0, 0);
    __syncthreads();

    bf16x8 af[4], bfr[4];
#pragma unroll
    for (int mi = 0; mi < 4; ++mi)
      af[mi] = *(const bf16x8*)&lA[(arow + mi * 16) * BK + kk];
#pragma unroll
    for (int ni = 0; ni < 4; ++ni)
      bfr[ni] = *(const bf16x8*)&lB[(brow + ni * 16) * BK + kk];
#pragma unroll
    for (int mi = 0; mi < 4; ++mi)
#pragma unroll
      for (int ni = 0; ni < 4; ++ni)
        acc[mi][ni] = __builtin_amdgcn_mfma_f32_16x16x32_bf16(af[mi], bfr[ni],
                                                              acc[mi][ni], 0, 0, 0);
    __syncthreads();
  }

  const int crow0 = bm + wr + ((lane >> 4) << 2);
  const int ccol0 = bn + wc + (lane & 15);
  if (bn < 1024) {                      // ---- Q (scaled) ----
#pragma unroll
    for (int ni = 0; ni < 4; ++ni) {
      const int n = ccol0 + ni * 16;
      const float bv = bias[n];
#pragma unroll
      for (int mi = 0; mi < 4; ++mi) {
        const int m0 = crow0 + mi * 16;
#pragma unroll
        for (int r = 0; r < 4; ++r)
          qb[(size_t)(m0 + r) * 1024 + n] = f2bf((acc[mi][ni][r] + bv) * sc_val);
      }
    }
  } else if (bn < 2048) {               // ---- K fragment order ----
#pragma unroll
    for (int ni = 0; ni < 4; ++ni) {
      const int n  = ccol0 + ni * 16;
      const int hk = (n - 1024) >> 6;
      const int d  = (n - 1024) & 63;
      const int hh = d >> 5, qd = (d >> 3) & 3, j = d & 7;
      const float bv = bias[n];
#pragma unroll
      for (int mi = 0; mi < 4; ++mi) {
#pragma unroll
        for (int r = 0; r < 4; ++r) {
          const int t  = crow0 + mi * 16 + r;
          const int bb = t >> 11, tt = t & 2047;
          const int kt = tt >> 6, mm = (tt >> 4) & 3, l = tt & 15;
          KF[((size_t)((bb * 16 + hk) * 32 + kt) * 8 + mm * 2 + hh) * 512 +
             (qd * 16 + l) * 8 + j] = f2bf(acc[mi][ni][r] + bv);
        }
      }
    }
  } else {                              // ---- V fragment order (k-perm) ----
#pragma unroll
    for (int ni = 0; ni < 4; ++ni) {
      const int n  = ccol0 + ni * 16;
      const int hv = (n - 2048) >> 6;
      const int d  = (n - 2048) & 63;
      const int di = d >> 4, l = d & 15;
      const float bv = bias[n];
#pragma unroll
      for (int mi = 0; mi < 4; ++mi) {
#pragma unroll
        for (int r = 0; r < 4; ++r) {
          const int t  = crow0 + mi * 16 + r;
          const int bb = t >> 11, tt = t & 2047;
          const int kt = tt >> 6, to = tt & 63;
          const int mq = to >> 4, qd2 = (to >> 2) & 3, rr = to & 3;
          const int hh = mq >> 1, j = (mq & 1) * 4 + rr;
          VF[((size_t)((bb * 16 + hv) * 32 + kt) * 8 + hh * 4 + di) * 512 +
             (qd2 * 16 + l) * 8 + j] = f2bf(acc[mi][ni][r] + bv);
        }
      }
    }
  }
}

// ---------------- Proj GEMM: 128x64 tile, fp32 out --------------------------
__global__ __launch_bounds__(256) void gemm_proj(const u16* __restrict__ A,
                                                 const u16* __restrict__ Bt,
                                                 const float* __restrict__ bias,
                                                 float* __restrict__ C) {
  constexpr int BM = 128, BN = 64, BK = 32;
  constexpr int K = 1024, N = 1024;
  __shared__ __align__(16) u16 lA[BM * BK];
  __shared__ __align__(16) u16 lB[BN * BK];
  const int tid  = threadIdx.x;
  const int lane = tid & 63;
  const int wave = tid >> 6;
  const int bm = blockIdx.x * BM;
  const int bn = blockIdx.y * BN;
  const int wr = wave * 32;

  f32x4 acc[2][4] = {};

  const int f0 = (wave << 10) + (lane << 4);
  const int f1 = f0 + 4096;
  const int ar0 = f0 >> 6, ac0 = (f0 & 63) >> 1;
  const int ar1 = f1 >> 6, ac1 = (f1 & 63) >> 1;

  const int arow = wr + (lane & 15);
  const int brow = (lane & 15);
  const int kk   = (lane >> 4) << 3;

  for (int k0 = 0; k0 < K; k0 += BK) {
    __builtin_amdgcn_global_load_lds((AS1 const void*)(A + (size_t)(bm + ar0) * K + k0 + ac0),
                                     (AS3 void*)(lA + (wave << 9)), 16, 0, 0);
    __builtin_amdgcn_global_load_lds((AS1 const void*)(A + (size_t)(bm + ar1) * K + k0 + ac1),
                                     (AS3 void*)(lA + ((wave + 4) << 9)), 16, 0, 0);
    __builtin_amdgcn_global_load_lds((AS1 const void*)(Bt + (size_t)(bn + ar0) * K + k0 + ac0),
                                     (AS3 void*)(lB + (wave << 9)), 16, 0, 0);
    __syncthreads();

    bf16x8 af[2], bfr[4];
#pragma unroll
    for (int mi = 0; mi < 2; ++mi)
      af[mi] = *(const bf16x8*)&lA[(arow + mi * 16) * BK + kk];
#pragma unroll
    for (int ni = 0; ni < 4; ++ni)
      bfr[ni] = *(const bf16x8*)&lB[(brow + ni * 16) * BK + kk];
#pragma unroll
    for (int mi = 0; mi < 2; ++mi)
#pragma unroll
      for (int ni = 0; ni < 4; ++ni)
        acc[mi][ni] = __builtin_amdgcn_mfma_f32_16x16x32_bf16(af[mi], bfr[ni],
                                                              acc[mi][ni], 0, 0, 0);
    __syncthreads();
  }

  const int crow0 = bm + wr + ((lane >> 4) << 2);
  const int ccol0 = bn + (lane & 15);
#pragma unroll
  for (int ni = 0; ni < 4; ++ni) {
    const int n = ccol0 + ni * 16;
    const float bv = bias[n];
#pragma unroll
    for (int mi = 0; mi < 2; ++mi) {
      const int m0 = crow0 + mi * 16;
#pragma unroll
      for (int r = 0; r < 4; ++r)
        C[(size_t)(m0 + r) * N + n] = acc[mi][ni][r] + bv;
    }
  }
}

// ---------------- balanced MFMA flash attention -----------------------------
// grid (32 u, 32 bh); block 256 = 4 waves.
// wave w: g32 = (w&1) ? 63-u : u  (32 q rows at g32*32), par = w>>1.
// Wave iterates kt = par, par+2, ... <= ktmax(g32) -> every block does
// exactly 33 tiles.  ALL 16 frag loads (K and V) issue at tile top -- one
// vmcnt drain per tile (R8 lesson).  Parity partials combine exactly via LDS.
__global__ __launch_bounds__(256) void attn_bal(const u16* __restrict__ qb,
                                                const u16* __restrict__ KF,
                                                const u16* __restrict__ VF,
                                                u16* __restrict__ out) {
  const int u  = blockIdx.x;
  const int bh = blockIdx.y;
  const int b = bh >> 4, h = bh & 15;
  const int tid = threadIdx.x;
  const int lane = tid & 63;
  const int w    = tid >> 6;
  const int quad = lane >> 4;
  const int l15  = lane & 15;
  const int g32 = (w & 1) ? (63 - u) : u;
  const int par = w >> 1;
  const int q0 = g32 * 32;
  const int ktmax = g32 >> 1;

  __shared__ float CB[2][64][35];     // [unit][lane][32 accO + 2 lsum]

  // Q B-frags, held all kernel
  const u16* qbase = qb + (size_t)b * 2048 * 1024 + h * 64;
  bf16x8 qf[2][2];
#pragma unroll
  for (int g = 0; g < 2; ++g)
#pragma unroll
    for (int hh = 0; hh < 2; ++hh)
      qf[g][hh] = *(const bf16x8*)(qbase + (size_t)(q0 + g * 16 + l15) * 1024 +
                                   hh * 32 + quad * 8);

  const size_t fb = (size_t)bh * 32 * 4096 + lane * 8;
  const u16* kfb = KF + fb;
  const u16* vfb = VF + fb;

  f32x4 accO[2][4] = {};              // [g][di]: q=quad*4+r, d=di*16+l15
  float lrow[2] = {0.f, 0.f};

  for (int kt = par; kt <= ktmax; kt += 2) {
    const u16* kp = kfb + (size_t)kt * 4096;
    const u16* vp = vfb + (size_t)kt * 4096;
    // ALL frag loads at tile top: 16 outstanding, one drain.
    bf16x8 kfr[4][2], vfr[2][4];
#pragma unroll
    for (int m = 0; m < 4; ++m)
#pragma unroll
      for (int hh = 0; hh < 2; ++hh)
        kfr[m][hh] = *(const bf16x8*)(kp + (m * 2 + hh) * 512);
#pragma unroll
    for (int hh = 0; hh < 2; ++hh)
#pragma unroll
      for (int di = 0; di < 4; ++di)
        vfr[hh][di] = *(const bf16x8*)(vp + (hh * 4 + di) * 512);

    const bool diag = (kt == ktmax);
    bf16x8 ap[2][2];
#pragma unroll
    for (int g = 0; g < 2; ++g) {
      f32x4 sT[4] = {};
#pragma unroll
      for (int m = 0; m < 4; ++m) {
        sT[m] = __builtin_amdgcn_mfma_f32_16x16x32_bf16(kfr[m][0], qf[g][0], sT[m], 0, 0, 0);
        sT[m] = __builtin_amdgcn_mfma_f32_16x16x32_bf16(kfr[m][1], qf[g][1], sT[m], 0, 0, 0);
      }
      float pv[4][4];
      float ps = 0.f;
      if (diag) {                      // only the last tile pays mask ops
        const int qgl = q0 + g * 16 + l15;
#pragma unroll
        for (int m = 0; m < 4; ++m)
#pragma unroll
          for (int r = 0; r < 4; ++r) {
            const bool msk = (kt * 64 + m * 16 + quad * 4 + r) > qgl;
            const float p = msk ? 0.f : __builtin_amdgcn_exp2f(sT[m][r]);
            pv[m][r] = p;
            ps += p;
          }
      } else {
#pragma unroll
        for (int m = 0; m < 4; ++m)
#pragma unroll
          for (int r = 0; r < 4; ++r) {
            const float p = __builtin_amdgcn_exp2f(sT[m][r]);
            pv[m][r] = p;
            ps += p;
          }
      }
      ps += __shfl_xor(ps, 16);
      ps += __shfl_xor(ps, 32);
      lrow[g] += ps;
      union { u32 u4[4]; bf16x8 v; } t0, t1;
      t0.u4[0] = pack2bf(pv[0][0], pv[0][1]);
      t0.u4[1] = pack2bf(pv[0][2], pv[0][3]);
      t0.u4[2] = pack2bf(pv[1][0], pv[1][1]);
      t0.u4[3] = pack2bf(pv[1][2], pv[1][3]);
      t1.u4[0] = pack2bf(pv[2][0], pv[2][1]);
      t1.u4[1] = pack2bf(pv[2][2], pv[2][3]);
      t1.u4[2] = pack2bf(pv[3][0], pv[3][1]);
      t1.u4[3] = pack2bf(pv[3][2], pv[3][3]);
      ap[g][0] = t0.v;
      ap[g][1] = t1.v;
    }

    // O += P.V
#pragma unroll
    for (int hh = 0; hh < 2; ++hh)
#pragma unroll
      for (int di = 0; di < 4; ++di) {
        bf16x8 bv = vfr[hh][di];
#pragma unroll
        for (int g = 0; g < 2; ++g)
          accO[g][di] = __builtin_amdgcn_mfma_f32_16x16x32_bf16(ap[g][hh], bv,
                                                               accO[g][di], 0, 0, 0);
      }
  }

  // ---- exact parity combine ----
  if (par) {
    float* cb = CB[w & 1][lane];
#pragma unroll
    for (int g = 0; g < 2; ++g)
#pragma unroll
      for (int di = 0; di < 4; ++di)
#pragma unroll
        for (int r = 0; r < 4; ++r)
          cb[g * 16 + di * 4 + r] = accO[g][di][r];
    cb[32] = lrow[0];
    cb[33] = lrow[1];
  }
  __syncthreads();
  if (!par) {
    const float* cb = CB[w & 1][lane];
#pragma unroll
    for (int g = 0; g < 2; ++g)
#pragma unroll
      for (int di = 0; di < 4; ++di)
#pragma unroll
        for (int r = 0; r < 4; ++r)
          accO[g][di][r] += cb[g * 16 + di * 4 + r];
    lrow[0] += cb[32];
    lrow[1] += cb[33];

#pragma unroll
    for (int g = 0; g < 2; ++g)
#pragma unroll
      for (int r = 0; r < 4; ++r) {
        const float lv = __shfl(lrow[g], quad * 4 + r);
        const float inv = 1.f / lv;
        const int q = q0 + g * 16 + quad * 4 + r;
        u16* op = out + (size_t)(b * 2048 + q) * 1024 + h * 64 + l15;
#pragma unroll
        for (int di = 0; di < 4; ++di)
          op[di * 16] = f2bf(accO[g][di][r] * inv);
      }
  }
}

// ---------------------------------------------------------------------------
extern "C" void kernel_launch(void* const* d_in, const int* in_sizes, int n_in,
                              void* d_out, int out_size, void* d_ws, size_t ws_size,
                              hipStream_t stream) {
  const float* x     = (const float*)d_in[0];
  const float* Wqkv  = (const float*)d_in[1];
  const float* bqkv  = (const float*)d_in[2];
  const float* Wproj = (const float*)d_in[3];
  const float* bproj = (const float*)d_in[4];
  float* out = (float*)d_out;

  char* ws = (char*)d_ws;
  u16* xb     = (u16*)(ws);                 //  8 MB  x bf16 [4096,1024]
  u16* wqkvT  = (u16*)(ws + 8388608);       //  6 MB  Wqkv^T bf16 [3072,1024]
  u16* wprojT = (u16*)(ws + 14680064);      //  2 MB  Wproj^T bf16 [1024,1024]
  u16* qb     = (u16*)(ws + 16777216);      //  8 MB  Q bf16 [4096,1024] (pre-scaled)
  u16* KF     = (u16*)(ws + 25165824);      //  8 MB  K fragment-order
  u16* VF     = (u16*)(ws + 33554432);      //  8 MB  V fragment-order (k-perm)
  u16* att    = (u16*)(ws + 41943040);      //  8 MB  attn out bf16 [4096,1024]

  constexpr float cs = 0.18033688011f;      // log2(e)/8

  prep<<<8192, 256, 0, stream>>>(x, xb, Wqkv, wqkvT, Wproj, wprojT);

  gemm_qkv<<<dim3(32, 24), 256, 0, stream>>>(xb, wqkvT, bqkv, qb, KF, VF, cs);

  attn_bal<<<dim3(32, 32), 256, 0, stream>>>(qb, KF, VF, att);

  gemm_proj<<<dim3(32, 16), 256, 0, stream>>>(att, wprojT, bproj, out);
}

// Round 10
// 186.087 us; speedup vs baseline: 1.4086x; 1.0530x over previous
//
#include <hip/hip_runtime.h>
#include <hip/hip_bf16.h>
#include <cstdint>

// ---------------------------------------------------------------------------
// CausalSelfAttention: x@Wqkv+b -> heads -> causal flash attn -> @Wproj+b
// B=2 T=2048 C=1024 H=16 Dh=64.
// Attention: barrier-light MFMA on fragment-order K/V (KF/VF written by the
// QKV GEMM epilogue), S^T = K.Q^T, exp2-domain softmax, no running max.
// Load balance: wave = (32-row q-group, k-parity); block pairs (u, 63-u) x
// parities -> every block does exactly 33 tiles; parity partials combine
// exactly in LDS.
// HARD-WON NOTES:
//  - R7: __launch_bounds__(256,4) forced VGPR=64 -> 380MB scratch spills.
//  - R8: V-frag loads after softmax doubled per-tile exposed latency.
//  - R10: K-frags pipelined one tile ahead (kt+2); ps tree-summed (fp adds
//    are not reassociable by the compiler); l-reduction shuffles deferred to
//    epilogue.  These target the ~460 cyc/tile of serial-chain stall.
// ---------------------------------------------------------------------------

using u16 = unsigned short;
using u32 = unsigned int;

typedef __bf16 bf16x8 __attribute__((ext_vector_type(8)));
typedef float f32x4 __attribute__((ext_vector_type(4)));

#define AS1 __attribute__((address_space(1)))
#define AS3 __attribute__((address_space(3)))

__device__ __forceinline__ u16 f2bf(float f) {
  u32 u = __float_as_uint(f);
  u += 0x7fffu + ((u >> 16) & 1u);   // RTNE
  return (u16)(u >> 16);
}
// pack two positive floats -> two bf16
__device__ __forceinline__ u32 pack2bf(float a, float b) {
  u32 ua = __float_as_uint(a) + 0x8000u;
  u32 ub = __float_as_uint(b) + 0x8000u;
  return (ua >> 16) | (ub & 0xffff0000u);
}

// ---------------- prep: cvt x->bf16 (blocks 0..4095) + W transposes ---------
__global__ __launch_bounds__(256) void prep(const float* __restrict__ x,
                                            u16* __restrict__ xb,
                                            const float* __restrict__ W0,
                                            u16* __restrict__ T0,
                                            const float* __restrict__ W1,
                                            u16* __restrict__ T1) {
  const int bx = blockIdx.x;
  const int tid = threadIdx.x;
  if (bx < 4096) {
    const int i = bx * 256 + tid;
    float4 v = ((const float4*)x)[i];
    ushort4 o;
    o.x = f2bf(v.x); o.y = f2bf(v.y); o.z = f2bf(v.z); o.w = f2bf(v.w);
    ((ushort4*)xb)[i] = o;
    return;
  }
  __shared__ float t[32][33];
  const int idx = bx - 4096;          // 128 n-tiles x 32 k-tiles
  const int bxx = idx & 127, by = idx >> 7;
  const float* W; u16* Wt; int N, n0;
  if (bxx < 96) { W = W0; Wt = T0; N = 3072; n0 = bxx * 32; }
  else          { W = W1; Wt = T1; N = 1024; n0 = (bxx - 96) * 32; }
  const int k0 = by * 32;
  const int tx = tid & 31, ty = tid >> 5;
#pragma unroll
  for (int i = 0; i < 4; ++i)
    t[ty + i * 8][tx] = W[(size_t)(k0 + ty + i * 8) * N + n0 + tx];
  __syncthreads();
#pragma unroll
  for (int i = 0; i < 4; ++i)
    Wt[(size_t)(n0 + ty + i * 8) * 1024 + k0 + tx] = f2bf(t[tx][ty + i * 8]);
}

// ---------------- QKV GEMM: 128x128 tile (m97 structure) --------------------
// n<1024: Q (scaled by cs) -> qb[4096][1024]
// 1024<=n<2048: K -> KF fragment order [bh][kt][m][hh][lane][8]
// n>=2048:     V -> VF fragment order [bh][kt][hh][di][lane][8] (k-permuted)
__global__ __launch_bounds__(256) void gemm_qkv(const u16* __restrict__ A,
                                                const u16* __restrict__ Bt,
                                                const float* __restrict__ bias,
                                                u16* __restrict__ qb,
                                                u16* __restrict__ KF,
                                                u16* __restrict__ VF,
                                                float sc_val) {
  constexpr int BM = 128, BK = 32;
  constexpr int K = 1024;
  __shared__ __align__(16) u16 lA[BM * BK];
  __shared__ __align__(16) u16 lB[BM * BK];
  const int tid  = threadIdx.x;
  const int lane = tid & 63;
  const int wave = tid >> 6;
  const int bm = blockIdx.x * BM;
  const int bn = blockIdx.y * BM;
  const int wr = (wave >> 1) * 64;
  const int wc = (wave & 1) * 64;

  f32x4 acc[4][4] = {};

  const int f0 = (wave << 10) + (lane << 4);
  const int f1 = f0 + 4096;
  const int r0 = f0 >> 6, c0 = (f0 & 63) >> 1;
  const int r1 = f1 >> 6, c1 = (f1 & 63) >> 1;

  const int arow = wr + (lane & 15);
  const int brow = wc + (lane & 15);
  const int kk   = (lane >> 4) << 3;

  for (int k0 = 0; k0 < K; k0 += BK) {
    __builtin_amdgcn_global_load_lds((AS1 const void*)(A + (size_t)(bm + r0) * K + k0 + c0),
                                     (AS3 void*)(lA + (wave << 9)), 16, 0, 0);
    __builtin_amdgcn_global_load_lds((AS1 const void*)(A + (size_t)(bm + r1) * K + k0 + c1),
                                     (AS3 void*)(lA + ((wave + 4) << 9)), 16, 0, 0);
    __builtin_amdgcn_global_load_lds((AS1 const void*)(Bt + (size_t)(bn + r0) * K + k0 + c0),
                                     (AS3 void*)(lB + (wave << 9)), 16, 0, 0);
    __builtin_amdgcn_global_load_lds((AS1 const void*)(Bt + (size_t)(bn + r1) * K + k0 + c1),
                                     (AS3 void*)(lB + ((wave + 4) << 9)), 16, 0, 0);
    __syncthreads();

    bf16x8 af[4], bfr[4];
#pragma unroll
    for (int mi = 0; mi < 4; ++mi)
      af[mi] = *(const bf16x8*)&lA[(arow + mi * 16) * BK + kk];
#pragma unroll
    for (int ni = 0; ni < 4; ++ni)
      bfr[ni] = *(const bf16x8*)&lB[(brow + ni * 16) * BK + kk];
#pragma unroll
    for (int mi = 0; mi < 4; ++mi)
#pragma unroll
      for (int ni = 0; ni < 4; ++ni)
        acc[mi][ni] = __builtin_amdgcn_mfma_f32_16x16x32_bf16(af[mi], bfr[ni],
                                                              acc[mi][ni], 0, 0, 0);
    __syncthreads();
  }

  const int crow0 = bm + wr + ((lane >> 4) << 2);
  const int ccol0 = bn + wc + (lane & 15);
  if (bn < 1024) {                      // ---- Q (scaled) ----
#pragma unroll
    for (int ni = 0; ni < 4; ++ni) {
      const int n = ccol0 + ni * 16;
      const float bv = bias[n];
#pragma unroll
      for (int mi = 0; mi < 4; ++mi) {
        const int m0 = crow0 + mi * 16;
#pragma unroll
        for (int r = 0; r < 4; ++r)
          qb[(size_t)(m0 + r) * 1024 + n] = f2bf((acc[mi][ni][r] + bv) * sc_val);
      }
    }
  } else if (bn < 2048) {               // ---- K fragment order ----
#pragma unroll
    for (int ni = 0; ni < 4; ++ni) {
      const int n  = ccol0 + ni * 16;
      const int hk = (n - 1024) >> 6;
      const int d  = (n - 1024) & 63;
      const int hh = d >> 5, qd = (d >> 3) & 3, j = d & 7;
      const float bv = bias[n];
#pragma unroll
      for (int mi = 0; mi < 4; ++mi) {
#pragma unroll
        for (int r = 0; r < 4; ++r) {
          const int t  = crow0 + mi * 16 + r;
          const int bb = t >> 11, tt = t & 2047;
          const int kt = tt >> 6, mm = (tt >> 4) & 3, l = tt & 15;
          KF[((size_t)((bb * 16 + hk) * 32 + kt) * 8 + mm * 2 + hh) * 512 +
             (qd * 16 + l) * 8 + j] = f2bf(acc[mi][ni][r] + bv);
        }
      }
    }
  } else {                              // ---- V fragment order (k-perm) ----
#pragma unroll
    for (int ni = 0; ni < 4; ++ni) {
      const int n  = ccol0 + ni * 16;
      const int hv = (n - 2048) >> 6;
      const int d  = (n - 2048) & 63;
      const int di = d >> 4, l = d & 15;
      const float bv = bias[n];
#pragma unroll
      for (int mi = 0; mi < 4; ++mi) {
#pragma unroll
        for (int r = 0; r < 4; ++r) {
          const int t  = crow0 + mi * 16 + r;
          const int bb = t >> 11, tt = t & 2047;
          const int kt = tt >> 6, to = tt & 63;
          const int mq = to >> 4, qd2 = (to >> 2) & 3, rr = to & 3;
          const int hh = mq >> 1, j = (mq & 1) * 4 + rr;
          VF[((size_t)((bb * 16 + hv) * 32 + kt) * 8 + hh * 4 + di) * 512 +
             (qd2 * 16 + l) * 8 + j] = f2bf(acc[mi][ni][r] + bv);
        }
      }
    }
  }
}

// ---------------- Proj GEMM: 128x64 tile, fp32 out --------------------------
__global__ __launch_bounds__(256) void gemm_proj(const u16* __restrict__ A,
                                                 const u16* __restrict__ Bt,
                                                 const float* __restrict__ bias,
                                                 float* __restrict__ C) {
  constexpr int BM = 128, BN = 64, BK = 32;
  constexpr int K = 1024, N = 1024;
  __shared__ __align__(16) u16 lA[BM * BK];
  __shared__ __align__(16) u16 lB[BN * BK];
  const int tid  = threadIdx.x;
  const int lane = tid & 63;
  const int wave = tid >> 6;
  const int bm = blockIdx.x * BM;
  const int bn = blockIdx.y * BN;
  const int wr = wave * 32;

  f32x4 acc[2][4] = {};

  const int f0 = (wave << 10) + (lane << 4);
  const int f1 = f0 + 4096;
  const int ar0 = f0 >> 6, ac0 = (f0 & 63) >> 1;
  const int ar1 = f1 >> 6, ac1 = (f1 & 63) >> 1;

  const int arow = wr + (lane & 15);
  const int brow = (lane & 15);
  const int kk   = (lane >> 4) << 3;

  for (int k0 = 0; k0 < K; k0 += BK) {
    __builtin_amdgcn_global_load_lds((AS1 const void*)(A + (size_t)(bm + ar0) * K + k0 + ac0),
                                     (AS3 void*)(lA + (wave << 9)), 16, 0, 0);
    __builtin_amdgcn_global_load_lds((AS1 const void*)(A + (size_t)(bm + ar1) * K + k0 + ac1),
                                     (AS3 void*)(lA + ((wave + 4) << 9)), 16, 0, 0);
    __builtin_amdgcn_global_load_lds((AS1 const void*)(Bt + (size_t)(bn + ar0) * K + k0 + ac0),
                                     (AS3 void*)(lB + (wave << 9)), 16, 0, 0);
    __syncthreads();

    bf16x8 af[2], bfr[4];
#pragma unroll
    for (int mi = 0; mi < 2; ++mi)
      af[mi] = *(const bf16x8*)&lA[(arow + mi * 16) * BK + kk];
#pragma unroll
    for (int ni = 0; ni < 4; ++ni)
      bfr[ni] = *(const bf16x8*)&lB[(brow + ni * 16) * BK + kk];
#pragma unroll
    for (int mi = 0; mi < 2; ++mi)
#pragma unroll
      for (int ni = 0; ni < 4; ++ni)
        acc[mi][ni] = __builtin_amdgcn_mfma_f32_16x16x32_bf16(af[mi], bfr[ni],
                                                              acc[mi][ni], 0, 0, 0);
    __syncthreads();
  }

  const int crow0 = bm + wr + ((lane >> 4) << 2);
  const int ccol0 = bn + (lane & 15);
#pragma unroll
  for (int ni = 0; ni < 4; ++ni) {
    const int n = ccol0 + ni * 16;
    const float bv = bias[n];
#pragma unroll
    for (int mi = 0; mi < 2; ++mi) {
      const int m0 = crow0 + mi * 16;
#pragma unroll
      for (int r = 0; r < 4; ++r)
        C[(size_t)(m0 + r) * N + n] = acc[mi][ni][r] + bv;
    }
  }
}

// ---------------- balanced pipelined MFMA flash attention -------------------
// grid (32 u, 32 bh); block 256 = 4 waves.
// wave w: g32 = (w&1) ? 63-u : u, par = w>>1; kt = par, par+2, ... <= ktmax.
// Per tile: V-frags load at top; K-frags for kt+2 load right after (depth-2
// pipeline, K used one full tile after issue).  Softmax: tree-summed ps,
// per-lane l accumulation (cross-lane reduction deferred to epilogue).
__global__ __launch_bounds__(256) void attn_bal(const u16* __restrict__ qb,
                                                const u16* __restrict__ KF,
                                                const u16* __restrict__ VF,
                                                u16* __restrict__ out) {
  const int u  = blockIdx.x;
  const int bh = blockIdx.y;
  const int b = bh >> 4, h = bh & 15;
  const int tid = threadIdx.x;
  const int lane = tid & 63;
  const int w    = tid >> 6;
  const int quad = lane >> 4;
  const int l15  = lane & 15;
  const int g32 = (w & 1) ? (63 - u) : u;
  const int par = w >> 1;
  const int q0 = g32 * 32;
  const int ktmax = g32 >> 1;

  __shared__ float CB[2][64][35];     // [unit][lane][32 accO + 2 lsum]

  // Q B-frags, held all kernel
  const u16* qbase = qb + (size_t)b * 2048 * 1024 + h * 64;
  bf16x8 qf[2][2];
#pragma unroll
  for (int g = 0; g < 2; ++g)
#pragma unroll
    for (int hh = 0; hh < 2; ++hh)
      qf[g][hh] = *(const bf16x8*)(qbase + (size_t)(q0 + g * 16 + l15) * 1024 +
                                   hh * 32 + quad * 8);

  const size_t fb = (size_t)bh * 32 * 4096 + lane * 8;
  const u16* kfb = KF + fb;
  const u16* vfb = VF + fb;

  f32x4 accO[2][4] = {};              // [g][di]: q=quad*4+r, d=di*16+l15
  float lrow[2] = {0.f, 0.f};         // PER-LANE partials; reduced in epilogue

  // prologue: K-frags for first tile
  bf16x8 kcur[4][2];
  {
    const u16* kp = kfb + (size_t)par * 4096;
#pragma unroll
    for (int m = 0; m < 4; ++m)
#pragma unroll
      for (int hh = 0; hh < 2; ++hh)
        kcur[m][hh] = *(const bf16x8*)(kp + (m * 2 + hh) * 512);
  }

  for (int kt = par; kt <= ktmax; kt += 2) {
    // V-frags for current tile at top
    const u16* vp = vfb + (size_t)kt * 4096;
    bf16x8 vfr[2][4];
#pragma unroll
    for (int hh = 0; hh < 2; ++hh)
#pragma unroll
      for (int di = 0; di < 4; ++di)
        vfr[hh][di] = *(const bf16x8*)(vp + (hh * 4 + di) * 512);
    // K-frags for tile kt+2 (clamped) -- used NEXT iteration
    const int ktn = (kt + 2 <= ktmax) ? kt + 2 : ktmax;
    const u16* kpn = kfb + (size_t)ktn * 4096;
    bf16x8 knx[4][2];
#pragma unroll
    for (int m = 0; m < 4; ++m)
#pragma unroll
      for (int hh = 0; hh < 2; ++hh)
        knx[m][hh] = *(const bf16x8*)(kpn + (m * 2 + hh) * 512);

    const bool diag = (kt == ktmax);
    bf16x8 ap[2][2];
#pragma unroll
    for (int g = 0; g < 2; ++g) {
      f32x4 sT[4] = {};
#pragma unroll
      for (int m = 0; m < 4; ++m) {
        sT[m] = __builtin_amdgcn_mfma_f32_16x16x32_bf16(kcur[m][0], qf[g][0], sT[m], 0, 0, 0);
        sT[m] = __builtin_amdgcn_mfma_f32_16x16x32_bf16(kcur[m][1], qf[g][1], sT[m], 0, 0, 0);
      }
      float pv[4][4];
      if (diag) {                      // only the last tile pays mask ops
        const int qgl = q0 + g * 16 + l15;
#pragma unroll
        for (int m = 0; m < 4; ++m)
#pragma unroll
          for (int r = 0; r < 4; ++r) {
            const bool msk = (kt * 64 + m * 16 + quad * 4 + r) > qgl;
            pv[m][r] = msk ? 0.f : __builtin_amdgcn_exp2f(sT[m][r]);
          }
      } else {
#pragma unroll
        for (int m = 0; m < 4; ++m)
#pragma unroll
          for (int r = 0; r < 4; ++r)
            pv[m][r] = __builtin_amdgcn_exp2f(sT[m][r]);
      }
      // tree sum (fp adds not reassociable by compiler -- do it manually)
      const float s0 = (pv[0][0] + pv[0][1]) + (pv[0][2] + pv[0][3]);
      const float s1 = (pv[1][0] + pv[1][1]) + (pv[1][2] + pv[1][3]);
      const float s2 = (pv[2][0] + pv[2][1]) + (pv[2][2] + pv[2][3]);
      const float s3 = (pv[3][0] + pv[3][1]) + (pv[3][2] + pv[3][3]);
      lrow[g] += (s0 + s1) + (s2 + s3);

      union { u32 u4[4]; bf16x8 v; } t0, t1;
      t0.u4[0] = pack2bf(pv[0][0], pv[0][1]);
      t0.u4[1] = pack2bf(pv[0][2], pv[0][3]);
      t0.u4[2] = pack2bf(pv[1][0], pv[1][1]);
      t0.u4[3] = pack2bf(pv[1][2], pv[1][3]);
      t1.u4[0] = pack2bf(pv[2][0], pv[2][1]);
      t1.u4[1] = pack2bf(pv[2][2], pv[2][3]);
      t1.u4[2] = pack2bf(pv[3][0], pv[3][1]);
      t1.u4[3] = pack2bf(pv[3][2], pv[3][3]);
      ap[g][0] = t0.v;
      ap[g][1] = t1.v;
    }

    // O += P.V
#pragma unroll
    for (int hh = 0; hh < 2; ++hh)
#pragma unroll
      for (int di = 0; di < 4; ++di) {
        bf16x8 bv = vfr[hh][di];
#pragma unroll
        for (int g = 0; g < 2; ++g)
          accO[g][di] = __builtin_amdgcn_mfma_f32_16x16x32_bf16(ap[g][hh], bv,
                                                               accO[g][di], 0, 0, 0);
      }

    // rotate K pipeline
#pragma unroll
    for (int m = 0; m < 4; ++m)
#pragma unroll
      for (int hh = 0; hh < 2; ++hh)
        kcur[m][hh] = knx[m][hh];
  }

  // ---- exact parity combine (per-lane values) ----
  if (par) {
    float* cb = CB[w & 1][lane];
#pragma unroll
    for (int g = 0; g < 2; ++g)
#pragma unroll
      for (int di = 0; di < 4; ++di)
#pragma unroll
        for (int r = 0; r < 4; ++r)
          cb[g * 16 + di * 4 + r] = accO[g][di][r];
    cb[32] = lrow[0];
    cb[33] = lrow[1];
  }
  __syncthreads();
  if (!par) {
    const float* cb = CB[w & 1][lane];
#pragma unroll
    for (int g = 0; g < 2; ++g)
#pragma unroll
      for (int di = 0; di < 4; ++di)
#pragma unroll
        for (int r = 0; r < 4; ++r)
          accO[g][di][r] += cb[g * 16 + di * 4 + r];
    lrow[0] += cb[32];
    lrow[1] += cb[33];
    // cross-quad l reduction (deferred from the tile loop)
#pragma unroll
    for (int g = 0; g < 2; ++g) {
      lrow[g] += __shfl_xor(lrow[g], 16);
      lrow[g] += __shfl_xor(lrow[g], 32);
    }

#pragma unroll
    for (int g = 0; g < 2; ++g)
#pragma unroll
      for (int r = 0; r < 4; ++r) {
        const float lv = __shfl(lrow[g], quad * 4 + r);
        const float inv = 1.f / lv;
        const int q = q0 + g * 16 + quad * 4 + r;
        u16* op = out + (size_t)(b * 2048 + q) * 1024 + h * 64 + l15;
#pragma unroll
        for (int di = 0; di < 4; ++di)
          op[di * 16] = f2bf(accO[g][di][r] * inv);
      }
  }
}

// ---------------------------------------------------------------------------
extern "C" void kernel_launch(void* const* d_in, const int* in_sizes, int n_in,
                              void* d_out, int out_size, void* d_ws, size_t ws_size,
                              hipStream_t stream) {
  const float* x     = (const float*)d_in[0];
  const float* Wqkv  = (const float*)d_in[1];
  const float* bqkv  = (const float*)d_in[2];
  const float* Wproj = (const float*)d_in[3];
  const float* bproj = (const float*)d_in[4];
  float* out = (float*)d_out;

  char* ws = (char*)d_ws;
  u16* xb     = (u16*)(ws);                 //  8 MB  x bf16 [4096,1024]
  u16* wqkvT  = (u16*)(ws + 8388608);       //  6 MB  Wqkv^T bf16 [3072,1024]
  u16* wprojT = (u16*)(ws + 14680064);      //  2 MB  Wproj^T bf16 [1024,1024]
  u16* qb     = (u16*)(ws + 16777216);      //  8 MB  Q bf16 [4096,1024] (pre-scaled)
  u16* KF     = (u16*)(ws + 25165824);      //  8 MB  K fragment-order
  u16* VF     = (u16*)(ws + 33554432);      //  8 MB  V fragment-order (k-perm)
  u16* att    = (u16*)(ws + 41943040);      //  8 MB  attn out bf16 [4096,1024]

  constexpr float cs = 0.18033688011f;      // log2(e)/8

  prep<<<8192, 256, 0, stream>>>(x, xb, Wqkv, wqkvT, Wproj, wprojT);

  gemm_qkv<<<dim3(32, 24), 256, 0, stream>>>(xb, wqkvT, bqkv, qb, KF, VF, cs);

  attn_bal<<<dim3(32, 32), 256, 0, stream>>>(qb, KF, VF, att);

  gemm_proj<<<dim3(32, 16), 256, 0, stream>>>(att, wprojT, bproj, out);
}